// Round 4
// baseline (95.676 us; speedup 1.0000x reference)
//
#include <hip/hip_runtime.h>
#include <math.h>

// RBF covariance: out[n][m] = var * exp(-0.5 * ||x[n]/s - xx[m]/s||^2),
// s = softplus(scale_raw), var = softplus(variance_raw), D = 8.
//
// log2-domain formulation (constants folded):
//   a' = (x/s)*sqrt(log2e), b' = (xx/s)*sqrt(log2e)
//   arg = (log2(var) - 0.5||a'||^2) + a'.b' - 0.5||b'||^2
//   out = exp2(min(arg, log2(var)))
//
// Round-4 geometry: 256-thread block -> 8 (n) x 1024 (m); thread owns 4
// CONTIGUOUS m-columns. First config combining BOTH proven-good attributes:
//   * dwordx4 stores: lane i writes 16B at i*16 -> contiguous 1 KiB/wave
//   * 2048 blocks (8/CU) + __launch_bounds__(256,8) -> 32 waves/CU
//     (requires <=64 VGPR; b=32, h=4, acc=4, a_=8, addr ~8 => ~58)
// s_c is read per-iter from LDS (broadcast b32) rather than hoisted to regs,
// deliberately, to stay under the 64-VGPR occupancy cliff.

#define TILE_N 8
#define D 8
#define BLOCK 256
#define M_PER_T 4
#define M_PER_BLOCK (BLOCK * M_PER_T)   // 1024

typedef float v2f __attribute__((ext_vector_type(2)));
typedef float v4f __attribute__((ext_vector_type(4)));

// softplus via hw exp2/log: max(z,0) + ln2*log2(1 + exp2(-|z|*log2e))
__device__ __forceinline__ float fast_softplus(float z) {
    const float LOG2E = 1.4426950408889634f;
    const float LN2   = 0.6931471805599453f;
    const float t = __builtin_amdgcn_exp2f(-fabsf(z) * LOG2E);
    return fmaxf(z, 0.0f) + LN2 * __builtin_amdgcn_logf(1.0f + t);
}

__global__ __launch_bounds__(BLOCK, 8) void rbf_kernel(
    const float* __restrict__ x,          // (N, 8)
    const float* __restrict__ xx,         // (M, 8)
    const float* __restrict__ scale_raw,  // (8,)
    const float* __restrict__ var_raw,    // (1,)
    float* __restrict__ out,              // (N, M)
    int N, int M)
{
    __shared__ float s_a[TILE_N][D];   // pre-scaled x rows
    __shared__ float s_c[TILE_N];      // log2(var) - 0.5*||a'||^2

    const int tid = threadIdx.x;
    const int m0 = blockIdx.x * M_PER_BLOCK + tid * M_PER_T;
    const int n0 = blockIdx.y * TILE_N;

    const float SQ_L2E = 1.2011224087864498f;   // sqrt(log2 e)

    // ---- hyperparameters, redundantly per-thread (broadcast loads, no barrier)
    float rs[D];   // statically indexed only; dead after prologue
    {
        const float4 s0 = *(const float4*)(scale_raw);
        const float4 s1 = *(const float4*)(scale_raw + 4);
        rs[0] = SQ_L2E / fast_softplus(s0.x);
        rs[1] = SQ_L2E / fast_softplus(s0.y);
        rs[2] = SQ_L2E / fast_softplus(s0.z);
        rs[3] = SQ_L2E / fast_softplus(s0.w);
        rs[4] = SQ_L2E / fast_softplus(s1.x);
        rs[5] = SQ_L2E / fast_softplus(s1.y);
        rs[6] = SQ_L2E / fast_softplus(s1.z);
        rs[7] = SQ_L2E / fast_softplus(s1.w);
    }
    const float l2v = __builtin_amdgcn_logf(fast_softplus(var_raw[0]));

    // ---- stage a-rows (64 threads) and row constants (8 threads), one barrier
    if (tid < TILE_N * D) {                        // 64 threads, one element each
        const int r = tid >> 3, c = tid & 7;
        const float rsc = SQ_L2E / fast_softplus(scale_raw[c]);
        s_a[r][c] = x[(n0 + r) * D + c] * rsc;
    } else if (tid < TILE_N * D + TILE_N) {        // 8 threads: row norms
        const int r = tid - TILE_N * D;
        const float4 lo = *(const float4*)(x + (size_t)(n0 + r) * D);
        const float4 hi = *(const float4*)(x + (size_t)(n0 + r) * D + 4);
        const float a0 = lo.x * rs[0], a1 = lo.y * rs[1];
        const float a2 = lo.z * rs[2], a3 = lo.w * rs[3];
        const float a4 = hi.x * rs[4], a5 = hi.y * rs[5];
        const float a6 = hi.z * rs[6], a7 = hi.w * rs[7];
        float s = a0 * a0;
        s = fmaf(a1, a1, s); s = fmaf(a2, a2, s); s = fmaf(a3, a3, s);
        s = fmaf(a4, a4, s); s = fmaf(a5, a5, s); s = fmaf(a6, a6, s);
        s = fmaf(a7, a7, s);
        s_c[r] = l2v - 0.5f * s;
    }

    // ---- 4 scaled xx rows directly into packed registers
    v2f b01[D], b23[D];
    {
        const float* xxp = xx + (size_t)m0 * D;
        const float4 e0 = *(const float4*)(xxp);           // row 0
        const float4 e1 = *(const float4*)(xxp + 4);
        const float4 f0 = *(const float4*)(xxp + D);       // row 1
        const float4 f1 = *(const float4*)(xxp + D + 4);
        const float4 g0 = *(const float4*)(xxp + 2 * D);   // row 2
        const float4 g1 = *(const float4*)(xxp + 2 * D + 4);
        const float4 k0 = *(const float4*)(xxp + 3 * D);   // row 3
        const float4 k1 = *(const float4*)(xxp + 3 * D + 4);
        b01[0] = (v2f){e0.x, f0.x} * rs[0];
        b01[1] = (v2f){e0.y, f0.y} * rs[1];
        b01[2] = (v2f){e0.z, f0.z} * rs[2];
        b01[3] = (v2f){e0.w, f0.w} * rs[3];
        b01[4] = (v2f){e1.x, f1.x} * rs[4];
        b01[5] = (v2f){e1.y, f1.y} * rs[5];
        b01[6] = (v2f){e1.z, f1.z} * rs[6];
        b01[7] = (v2f){e1.w, f1.w} * rs[7];
        b23[0] = (v2f){g0.x, k0.x} * rs[0];
        b23[1] = (v2f){g0.y, k0.y} * rs[1];
        b23[2] = (v2f){g0.z, k0.z} * rs[2];
        b23[3] = (v2f){g0.w, k0.w} * rs[3];
        b23[4] = (v2f){g1.x, k1.x} * rs[4];
        b23[5] = (v2f){g1.y, k1.y} * rs[5];
        b23[6] = (v2f){g1.z, k1.z} * rs[6];
        b23[7] = (v2f){g1.w, k1.w} * rs[7];
    }
    // 0.5*||b'||^2 per owned column, packed
    v2f h01 = b01[0] * b01[0];
    v2f h23 = b23[0] * b23[0];
#pragma unroll
    for (int d = 1; d < D; ++d) {
        h01 = __builtin_elementwise_fma(b01[d], b01[d], h01);
        h23 = __builtin_elementwise_fma(b23[d], b23[d], h23);
    }
    h01 *= 0.5f; h23 *= 0.5f;

    __syncthreads();

    float* orow = out + (size_t)n0 * M + m0;
#pragma unroll
    for (int n = 0; n < TILE_N; ++n) {
        const float4 alo = *(const float4*)&s_a[n][0];   // broadcast ds_read_b128
        const float4 ahi = *(const float4*)&s_a[n][4];
        const float c = s_c[n];                          // broadcast ds_read_b32
        const float a_[D] = {alo.x, alo.y, alo.z, alo.w,
                             ahi.x, ahi.y, ahi.z, ahi.w};

        v2f acc01 = (v2f){c, c} - h01;
        v2f acc23 = (v2f){c, c} - h23;
#pragma unroll
        for (int d = 0; d < D; ++d) {
            const v2f av = (v2f){a_[d], a_[d]};
            acc01 = __builtin_elementwise_fma(av, b01[d], acc01);  // v_pk_fma_f32
            acc23 = __builtin_elementwise_fma(av, b23[d], acc23);
        }

        v4f r;
        r.x = __builtin_amdgcn_exp2f(fminf(acc01.x, l2v));
        r.y = __builtin_amdgcn_exp2f(fminf(acc01.y, l2v));
        r.z = __builtin_amdgcn_exp2f(fminf(acc23.x, l2v));
        r.w = __builtin_amdgcn_exp2f(fminf(acc23.y, l2v));
        *(v4f*)orow = r;                                 // contiguous 1 KiB / wave
        orow += M;
    }
}

extern "C" void kernel_launch(void* const* d_in, const int* in_sizes, int n_in,
                              void* d_out, int out_size, void* d_ws, size_t ws_size,
                              hipStream_t stream) {
    const float* x    = (const float*)d_in[0];
    const float* xx   = (const float*)d_in[1];
    const float* sraw = (const float*)d_in[2];
    const float* vraw = (const float*)d_in[3];
    float* out = (float*)d_out;

    const int N = in_sizes[0] / D;   // 4096
    const int M = in_sizes[1] / D;   // 4096

    dim3 grid(M / M_PER_BLOCK, N / TILE_N);   // (4, 512) = 2048 blocks
    rbf_kernel<<<grid, BLOCK, 0, stream>>>(x, xx, sraw, vraw, out, N, M);
}

// Round 5
// 88.340 us; speedup vs baseline: 1.0830x; 1.0830x over previous
//
#include <hip/hip_runtime.h>
#include <math.h>

// RBF covariance: out[n][m] = var * exp(-0.5 * ||x[n]/s - xx[m]/s||^2),
// s = softplus(scale_raw), var = softplus(variance_raw), D = 8.
//
// log2-domain formulation (constants folded):
//   a' = (x/s)*sqrt(log2e), b' = (xx/s)*sqrt(log2e)
//   arg = (log2(var) - 0.5||a'||^2) + a'.b' - 0.5||b'||^2
//   out = exp2(min(arg, log2(var)))
//
// Round-5 geometry: identical per-thread shape to round-3 (the best config:
// 2 contiguous m-cols/thread, b[]=16 VGPR, 32 waves/CU) but TILE_N 16->8,
// doubling the grid to 4096 blocks (16 assigned/CU, 32 waves resident,
// churning). Rationale: R3 had exactly one resident complement (8 blocks/CU)
// -> every CU's store pipe drains once per generation with nothing queued,
// and each block's serial prologue is exposed. Doubled turnover overlaps
// prologues with other blocks' epilogues and keeps stores fed.

#define TILE_N 8
#define D 8
#define BLOCK 256
#define M_PER_T 2
#define M_PER_BLOCK (BLOCK * M_PER_T)   // 512

typedef float v2f __attribute__((ext_vector_type(2)));

// softplus via hw exp2/log: max(z,0) + ln2*log2(1 + exp2(-|z|*log2e))
__device__ __forceinline__ float fast_softplus(float z) {
    const float LOG2E = 1.4426950408889634f;
    const float LN2   = 0.6931471805599453f;
    const float t = __builtin_amdgcn_exp2f(-fabsf(z) * LOG2E);
    return fmaxf(z, 0.0f) + LN2 * __builtin_amdgcn_logf(1.0f + t);
}

__global__ __launch_bounds__(BLOCK, 8) void rbf_kernel(
    const float* __restrict__ x,          // (N, 8)
    const float* __restrict__ xx,         // (M, 8)
    const float* __restrict__ scale_raw,  // (8,)
    const float* __restrict__ var_raw,    // (1,)
    float* __restrict__ out,              // (N, M)
    int N, int M)
{
    __shared__ float s_a[TILE_N][D];   // pre-scaled x rows
    __shared__ float s_c[TILE_N];      // log2(var) - 0.5*||a'||^2

    const int tid = threadIdx.x;
    const int m0 = blockIdx.x * M_PER_BLOCK + tid * M_PER_T;
    const int n0 = blockIdx.y * TILE_N;

    const float SQ_L2E = 1.2011224087864498f;   // sqrt(log2 e)

    // ---- hyperparameters, redundantly per-thread (broadcast loads, no barrier)
    float rs[D];   // statically indexed only; dead after prologue
    {
        const float4 s0 = *(const float4*)(scale_raw);
        const float4 s1 = *(const float4*)(scale_raw + 4);
        rs[0] = SQ_L2E / fast_softplus(s0.x);
        rs[1] = SQ_L2E / fast_softplus(s0.y);
        rs[2] = SQ_L2E / fast_softplus(s0.z);
        rs[3] = SQ_L2E / fast_softplus(s0.w);
        rs[4] = SQ_L2E / fast_softplus(s1.x);
        rs[5] = SQ_L2E / fast_softplus(s1.y);
        rs[6] = SQ_L2E / fast_softplus(s1.z);
        rs[7] = SQ_L2E / fast_softplus(s1.w);
    }
    const float l2v = __builtin_amdgcn_logf(fast_softplus(var_raw[0]));

    // ---- stage a-rows (64 threads) and row constants (8 threads), one barrier
    if (tid < TILE_N * D) {                        // 64 threads, one element each
        const int r = tid >> 3, c = tid & 7;
        const float rsc = SQ_L2E / fast_softplus(scale_raw[c]);
        s_a[r][c] = x[(n0 + r) * D + c] * rsc;
    } else if (tid < TILE_N * D + TILE_N) {        // 8 threads: row norms
        const int r = tid - TILE_N * D;
        const float4 lo = *(const float4*)(x + (size_t)(n0 + r) * D);
        const float4 hi = *(const float4*)(x + (size_t)(n0 + r) * D + 4);
        const float a0 = lo.x * rs[0], a1 = lo.y * rs[1];
        const float a2 = lo.z * rs[2], a3 = lo.w * rs[3];
        const float a4 = hi.x * rs[4], a5 = hi.y * rs[5];
        const float a6 = hi.z * rs[6], a7 = hi.w * rs[7];
        float s = a0 * a0;
        s = fmaf(a1, a1, s); s = fmaf(a2, a2, s); s = fmaf(a3, a3, s);
        s = fmaf(a4, a4, s); s = fmaf(a5, a5, s); s = fmaf(a6, a6, s);
        s = fmaf(a7, a7, s);
        s_c[r] = l2v - 0.5f * s;
    }

    // ---- 2 scaled xx rows into packed registers (pair = cols {m0, m0+1})
    v2f b[D];
    {
        const float* xxp = xx + (size_t)m0 * D;
        const float4 e0 = *(const float4*)(xxp);           // row m0
        const float4 e1 = *(const float4*)(xxp + 4);
        const float4 f0 = *(const float4*)(xxp + D);       // row m0+1
        const float4 f1 = *(const float4*)(xxp + D + 4);
        b[0] = (v2f){e0.x, f0.x} * rs[0];
        b[1] = (v2f){e0.y, f0.y} * rs[1];
        b[2] = (v2f){e0.z, f0.z} * rs[2];
        b[3] = (v2f){e0.w, f0.w} * rs[3];
        b[4] = (v2f){e1.x, f1.x} * rs[4];
        b[5] = (v2f){e1.y, f1.y} * rs[5];
        b[6] = (v2f){e1.z, f1.z} * rs[6];
        b[7] = (v2f){e1.w, f1.w} * rs[7];
    }
    // 0.5*||b'||^2 per owned column, packed
    v2f h = b[0] * b[0];
#pragma unroll
    for (int d = 1; d < D; ++d)
        h = __builtin_elementwise_fma(b[d], b[d], h);
    h *= 0.5f;

    __syncthreads();

    float* orow = out + (size_t)n0 * M + m0;
#pragma unroll
    for (int n = 0; n < TILE_N; ++n) {
        const float4 alo = *(const float4*)&s_a[n][0];   // broadcast ds_read_b128
        const float4 ahi = *(const float4*)&s_a[n][4];
        const float c = s_c[n];                          // broadcast ds_read_b32
        const float a_[D] = {alo.x, alo.y, alo.z, alo.w,
                             ahi.x, ahi.y, ahi.z, ahi.w};

        v2f acc = (v2f){c, c} - h;
#pragma unroll
        for (int d = 0; d < D; ++d) {
            const v2f av = (v2f){a_[d], a_[d]};
            acc = __builtin_elementwise_fma(av, b[d], acc);  // v_pk_fma_f32
        }

        v2f r;
        r.x = __builtin_amdgcn_exp2f(fminf(acc.x, l2v));
        r.y = __builtin_amdgcn_exp2f(fminf(acc.y, l2v));
        *(v2f*)orow = r;                                 // plain store, 512 B/wave
        orow += M;
    }
}

extern "C" void kernel_launch(void* const* d_in, const int* in_sizes, int n_in,
                              void* d_out, int out_size, void* d_ws, size_t ws_size,
                              hipStream_t stream) {
    const float* x    = (const float*)d_in[0];
    const float* xx   = (const float*)d_in[1];
    const float* sraw = (const float*)d_in[2];
    const float* vraw = (const float*)d_in[3];
    float* out = (float*)d_out;

    const int N = in_sizes[0] / D;   // 4096
    const int M = in_sizes[1] / D;   // 4096

    dim3 grid(M / M_PER_BLOCK, N / TILE_N);   // (8, 512) = 4096 blocks
    rbf_kernel<<<grid, BLOCK, 0, stream>>>(x, xx, sraw, vraw, out, N, M);
}

// Round 6
// 83.299 us; speedup vs baseline: 1.1486x; 1.0605x over previous
//
#include <hip/hip_runtime.h>
#include <math.h>

// RBF covariance: out[n][m] = var * exp(-0.5 * ||x[n]/s - xx[m]/s||^2),
// s = softplus(scale_raw), var = softplus(variance_raw), D = 8.
//
// log2-domain formulation (constants folded):
//   a' = (x/s)*sqrt(log2e), b' = (xx/s)*sqrt(log2e)
//   arg = (log2(var) - 0.5||a'||^2) + a'.b' - 0.5||b'||^2
//   out = exp2(min(arg, log2(var)))
//
// FINAL geometry (round-3, best measured: 83.4 us): 256-thread block ->
// 16 (n) x 512 (m); thread owns 2 CONTIGUOUS m-columns.
//   * b[] = 16 VGPR; __launch_bounds__(256,8) => <=64 VGPR => 32 waves/CU
//   * 2048 blocks = exactly 8/CU, one resident complement
//   * plain dwordx2 stores: lane i writes 8B at i*8 -> contiguous 512 B/wave
// Explored and rejected: 16 waves/CU (R0/R2: 86-88), 4096-block churn
// (R5: 88.3), M_PER_T=4 @ 32 waves (R4: spills, 95.7), 8-col strided
// stores (R1: 103.6).

#define TILE_N 16
#define D 8
#define BLOCK 256
#define M_PER_T 2
#define M_PER_BLOCK (BLOCK * M_PER_T)   // 512

typedef float v2f __attribute__((ext_vector_type(2)));

// softplus via hw exp2/log: max(z,0) + ln2*log2(1 + exp2(-|z|*log2e))
__device__ __forceinline__ float fast_softplus(float z) {
    const float LOG2E = 1.4426950408889634f;
    const float LN2   = 0.6931471805599453f;
    const float t = __builtin_amdgcn_exp2f(-fabsf(z) * LOG2E);
    return fmaxf(z, 0.0f) + LN2 * __builtin_amdgcn_logf(1.0f + t);
}

__global__ __launch_bounds__(BLOCK, 8) void rbf_kernel(
    const float* __restrict__ x,          // (N, 8)
    const float* __restrict__ xx,         // (M, 8)
    const float* __restrict__ scale_raw,  // (8,)
    const float* __restrict__ var_raw,    // (1,)
    float* __restrict__ out,              // (N, M)
    int N, int M)
{
    __shared__ float s_a[TILE_N][D];   // pre-scaled x rows
    __shared__ float s_c[TILE_N];      // log2(var) - 0.5*||a'||^2

    const int tid = threadIdx.x;
    const int m0 = blockIdx.x * M_PER_BLOCK + tid * M_PER_T;
    const int n0 = blockIdx.y * TILE_N;

    const float SQ_L2E = 1.2011224087864498f;   // sqrt(log2 e)

    // ---- hyperparameters, redundantly per-thread (broadcast loads, no barrier)
    float rs[D];   // statically indexed only; dead after prologue
    {
        const float4 s0 = *(const float4*)(scale_raw);
        const float4 s1 = *(const float4*)(scale_raw + 4);
        rs[0] = SQ_L2E / fast_softplus(s0.x);
        rs[1] = SQ_L2E / fast_softplus(s0.y);
        rs[2] = SQ_L2E / fast_softplus(s0.z);
        rs[3] = SQ_L2E / fast_softplus(s0.w);
        rs[4] = SQ_L2E / fast_softplus(s1.x);
        rs[5] = SQ_L2E / fast_softplus(s1.y);
        rs[6] = SQ_L2E / fast_softplus(s1.z);
        rs[7] = SQ_L2E / fast_softplus(s1.w);
    }
    const float l2v = __builtin_amdgcn_logf(fast_softplus(var_raw[0]));

    // ---- stage a-rows (128 threads) and row constants (16 threads), one barrier
    if (tid < TILE_N * D) {                        // 128 threads, one element each
        const int r = tid >> 3, c = tid & 7;
        const float rsc = SQ_L2E / fast_softplus(scale_raw[c]);
        s_a[r][c] = x[(n0 + r) * D + c] * rsc;
    } else if (tid < TILE_N * D + TILE_N) {        // 16 threads: row norms
        const int r = tid - TILE_N * D;
        const float4 lo = *(const float4*)(x + (size_t)(n0 + r) * D);
        const float4 hi = *(const float4*)(x + (size_t)(n0 + r) * D + 4);
        const float a0 = lo.x * rs[0], a1 = lo.y * rs[1];
        const float a2 = lo.z * rs[2], a3 = lo.w * rs[3];
        const float a4 = hi.x * rs[4], a5 = hi.y * rs[5];
        const float a6 = hi.z * rs[6], a7 = hi.w * rs[7];
        float s = a0 * a0;
        s = fmaf(a1, a1, s); s = fmaf(a2, a2, s); s = fmaf(a3, a3, s);
        s = fmaf(a4, a4, s); s = fmaf(a5, a5, s); s = fmaf(a6, a6, s);
        s = fmaf(a7, a7, s);
        s_c[r] = l2v - 0.5f * s;
    }

    // ---- 2 scaled xx rows into packed registers (pair = cols {m0, m0+1})
    v2f b[D];
    {
        const float* xxp = xx + (size_t)m0 * D;
        const float4 e0 = *(const float4*)(xxp);           // row m0
        const float4 e1 = *(const float4*)(xxp + 4);
        const float4 f0 = *(const float4*)(xxp + D);       // row m0+1
        const float4 f1 = *(const float4*)(xxp + D + 4);
        b[0] = (v2f){e0.x, f0.x} * rs[0];
        b[1] = (v2f){e0.y, f0.y} * rs[1];
        b[2] = (v2f){e0.z, f0.z} * rs[2];
        b[3] = (v2f){e0.w, f0.w} * rs[3];
        b[4] = (v2f){e1.x, f1.x} * rs[4];
        b[5] = (v2f){e1.y, f1.y} * rs[5];
        b[6] = (v2f){e1.z, f1.z} * rs[6];
        b[7] = (v2f){e1.w, f1.w} * rs[7];
    }
    // 0.5*||b'||^2 per owned column, packed
    v2f h = b[0] * b[0];
#pragma unroll
    for (int d = 1; d < D; ++d)
        h = __builtin_elementwise_fma(b[d], b[d], h);
    h *= 0.5f;

    __syncthreads();

    float* orow = out + (size_t)n0 * M + m0;
#pragma unroll
    for (int n = 0; n < TILE_N; ++n) {
        const float4 alo = *(const float4*)&s_a[n][0];   // broadcast ds_read_b128
        const float4 ahi = *(const float4*)&s_a[n][4];
        const float c = s_c[n];                          // broadcast ds_read_b32
        const float a_[D] = {alo.x, alo.y, alo.z, alo.w,
                             ahi.x, ahi.y, ahi.z, ahi.w};

        v2f acc = (v2f){c, c} - h;
#pragma unroll
        for (int d = 0; d < D; ++d) {
            const v2f av = (v2f){a_[d], a_[d]};
            acc = __builtin_elementwise_fma(av, b[d], acc);  // v_pk_fma_f32
        }

        v2f r;
        r.x = __builtin_amdgcn_exp2f(fminf(acc.x, l2v));
        r.y = __builtin_amdgcn_exp2f(fminf(acc.y, l2v));
        *(v2f*)orow = r;                                 // plain store, 512 B/wave
        orow += M;
    }
}

extern "C" void kernel_launch(void* const* d_in, const int* in_sizes, int n_in,
                              void* d_out, int out_size, void* d_ws, size_t ws_size,
                              hipStream_t stream) {
    const float* x    = (const float*)d_in[0];
    const float* xx   = (const float*)d_in[1];
    const float* sraw = (const float*)d_in[2];
    const float* vraw = (const float*)d_in[3];
    float* out = (float*)d_out;

    const int N = in_sizes[0] / D;   // 4096
    const int M = in_sizes[1] / D;   // 4096

    dim3 grid(M / M_PER_BLOCK, N / TILE_N);   // (8, 256) = 2048 blocks
    rbf_kernel<<<grid, BLOCK, 0, stream>>>(x, xx, sraw, vraw, out, N, M);
}